// Round 10
// baseline (332.115 us; speedup 1.0000x reference)
//
#include <hip/hip_runtime.h>
#include <hip/hip_bf16.h>

#define N_NODES 50000
#define E_EDGES 800000
#define ET (E_EDGES + N_NODES)   // with self-loops
#define HEADS 4
#define HC 128                    // HEADS * OUT_CH
#define NEG_SLOPE 0.2f
#define SCAN_B 256
#define NBLK ((N_NODES + SCAN_B - 1) / SCAN_B)   // 196 blocks per array

__device__ __forceinline__ unsigned short f2bf(float f) {
    unsigned u = __float_as_uint(f);
    unsigned r = u + 0x7FFFu + ((u >> 16) & 1u);
    return (unsigned short)(r >> 16);
}

// ---------------- GEMM: x = feat @ W, fused a_i/a_j epilogue ----------------
// (unchanged from round 7: shuffle-reduce epilogue, no atomics)
__global__ __launch_bounds__(256)
void gemm_kernel(const float* __restrict__ feat, const float* __restrict__ weight,
                 const float* __restrict__ att,
                 unsigned short* __restrict__ xb,    // bf16 x, [N][128]
                 float* __restrict__ a_i, float* __restrict__ a_j)
{
    __shared__ float sA[32][68];   // [k][row] transposed, BM=64
    __shared__ float sB[32][132];  // [k][col], BN=128
    const int t = threadIdx.x;
    const int row0 = blockIdx.x * 64;
    const int rg = t >> 4;   // 0..15 -> rows 4rg..4rg+3
    const int cg = t & 15;   // 0..15 -> cols 4cg..+3, 64+4cg..+3

    float acc[4][8];
#pragma unroll
    for (int i = 0; i < 4; i++)
#pragma unroll
        for (int j = 0; j < 8; j++) acc[i][j] = 0.f;

    for (int kc = 0; kc < 128; kc += 32) {
        __syncthreads();
#pragma unroll
        for (int q = 0; q < 2; q++) {          // stage feat tile (transposed)
            int qi = t + q * 256;              // 0..511
            int row = qi >> 3;                 // 0..63
            int kq = qi & 7;                   // 0..7
            int grow = row0 + row;
            float4 v = make_float4(0.f, 0.f, 0.f, 0.f);
            if (grow < N_NODES)
                v = *(const float4*)&feat[grow * 128 + kc + kq * 4];
            sA[kq * 4 + 0][row] = v.x; sA[kq * 4 + 1][row] = v.y;
            sA[kq * 4 + 2][row] = v.z; sA[kq * 4 + 3][row] = v.w;
        }
#pragma unroll
        for (int q = 0; q < 4; q++) {          // stage W tile
            int qi = t + q * 256;
            int k = qi >> 5;                   // 0..31
            int cq = qi & 31;                  // 0..31
            float4 v = *(const float4*)&weight[(kc + k) * 128 + cq * 4];
            *(float4*)&sB[k][cq * 4] = v;
        }
        __syncthreads();
#pragma unroll 4
        for (int k = 0; k < 32; k++) {
            float4 a0 = *(const float4*)&sA[k][4 * rg];
            float4 b0 = *(const float4*)&sB[k][4 * cg];
            float4 b1 = *(const float4*)&sB[k][64 + 4 * cg];
#define FMA_ROW(r, ar) \
            acc[r][0] = fmaf(ar, b0.x, acc[r][0]); \
            acc[r][1] = fmaf(ar, b0.y, acc[r][1]); \
            acc[r][2] = fmaf(ar, b0.z, acc[r][2]); \
            acc[r][3] = fmaf(ar, b0.w, acc[r][3]); \
            acc[r][4] = fmaf(ar, b1.x, acc[r][4]); \
            acc[r][5] = fmaf(ar, b1.y, acc[r][5]); \
            acc[r][6] = fmaf(ar, b1.z, acc[r][6]); \
            acc[r][7] = fmaf(ar, b1.w, acc[r][7]);
            FMA_ROW(0, a0.x)
            FMA_ROW(1, a0.y)
            FMA_ROW(2, a0.z)
            FMA_ROW(3, a0.w)
#undef FMA_ROW
        }
    }

    // epilogue: bf16 store + shuffle-reduced a_i/a_j (NO atomics)
    const int h0 = cg >> 3;              // head of col group 0 (0 or 1)
    const int cih = (4 * cg) & 31;       // col within head
    float ai_c[2][4], aj_c[2][4];
#pragma unroll
    for (int g = 0; g < 2; g++) {
        int h = h0 + g * 2;
#pragma unroll
        for (int j = 0; j < 4; j++) {
            ai_c[g][j] = att[h * 64 + cih + j];
            aj_c[g][j] = att[h * 64 + 32 + cih + j];
        }
    }
#pragma unroll
    for (int i = 0; i < 4; i++) {
        int row = row0 + 4 * rg + i;
        if (row >= N_NODES) continue;      // uniform across each 8-lane group
        unsigned p0 = (unsigned)f2bf(acc[i][0]) | ((unsigned)f2bf(acc[i][1]) << 16);
        unsigned p1 = (unsigned)f2bf(acc[i][2]) | ((unsigned)f2bf(acc[i][3]) << 16);
        unsigned p2 = (unsigned)f2bf(acc[i][4]) | ((unsigned)f2bf(acc[i][5]) << 16);
        unsigned p3 = (unsigned)f2bf(acc[i][6]) | ((unsigned)f2bf(acc[i][7]) << 16);
        uint2 q0; q0.x = p0; q0.y = p1;
        uint2 q1; q1.x = p2; q1.y = p3;
        *(uint2*)&xb[row * 128 + 4 * cg] = q0;
        *(uint2*)&xb[row * 128 + 64 + 4 * cg] = q1;

        float pi0 = 0.f, pj0 = 0.f, pi1 = 0.f, pj1 = 0.f;
#pragma unroll
        for (int j = 0; j < 4; j++) {
            pi0 = fmaf(acc[i][j], ai_c[0][j], pi0);
            pj0 = fmaf(acc[i][j], aj_c[0][j], pj0);
            pi1 = fmaf(acc[i][4 + j], ai_c[1][j], pi1);
            pj1 = fmaf(acc[i][4 + j], aj_c[1][j], pj1);
        }
        // butterfly over cg bits 0..2 (8 lanes hold one (row,head) partial)
#pragma unroll
        for (int m = 1; m <= 4; m <<= 1) {
            pi0 += __shfl_xor(pi0, m, 64);
            pj0 += __shfl_xor(pj0, m, 64);
            pi1 += __shfl_xor(pi1, m, 64);
            pj1 += __shfl_xor(pj1, m, 64);
        }
        if ((cg & 7) == 0) {               // cg==0 -> heads 0,2; cg==8 -> heads 1,3
            a_i[row * 4 + h0]     = pi0;
            a_i[row * 4 + h0 + 2] = pi1;
            a_j[row * 4 + h0]     = pj0;
            a_j[row * 4 + h0 + 2] = pj1;
        }
    }
}

// ---------------- rank pass: deg histograms, return-value = rank ------------
__global__ __launch_bounds__(256)
void rank_pass(const int* __restrict__ ei, int* __restrict__ deg_s,
               int* __restrict__ deg_d, unsigned short* __restrict__ rank_s,
               unsigned short* __restrict__ rank_d)
{
    int e = blockIdx.x * 256 + threadIdx.x;
    if (e >= ET) return;
    int s, d;
    if (e < E_EDGES) { s = ei[e]; d = ei[E_EDGES + e]; }
    else { s = d = e - E_EDGES; }
    rank_s[e] = (unsigned short)atomicAdd(&deg_s[s], 1);
    rank_d[e] = (unsigned short)atomicAdd(&deg_d[d], 1);
}

// ---------------- hierarchical scan (3-phase, multi-block) ------------------
// Phase A: per-block sums. Blocks [0,NBLK) -> deg_s, [NBLK,2*NBLK) -> deg_d.
__global__ __launch_bounds__(SCAN_B)
void partial_kernel(const int* __restrict__ deg_s, const int* __restrict__ deg_d,
                    int* __restrict__ partials)
{
    __shared__ int wsum[4];
    int half = (blockIdx.x < NBLK) ? 0 : 1;
    int blk = half ? (blockIdx.x - NBLK) : blockIdx.x;
    const int* deg = half ? deg_d : deg_s;
    int idx = blk * SCAN_B + threadIdx.x;
    int v = (idx < N_NODES) ? deg[idx] : 0;
#pragma unroll
    for (int m = 1; m < 64; m <<= 1) v += __shfl_xor(v, m, 64);
    int lane = threadIdx.x & 63, wid = threadIdx.x >> 6;
    if (lane == 0) wsum[wid] = v;
    __syncthreads();
    if (threadIdx.x == 0)
        partials[blockIdx.x] = wsum[0] + wsum[1] + wsum[2] + wsum[3];
}

// Phase B: single block scans both partial arrays (196 each) in LDS,
// writes exclusive block-offsets back in place + off[N] totals.
__global__ __launch_bounds__(512)
void scanp_kernel(int* __restrict__ partials, int* __restrict__ off_s,
                  int* __restrict__ off_d)
{
    __shared__ int sh[512];
    int t = threadIdx.x;
    int hf = t & 255;
    int v = 0;
    if (t < 256)      v = (hf < NBLK) ? partials[hf] : 0;
    else              v = (hf < NBLK) ? partials[NBLK + hf] : 0;
    sh[t] = v;
    __syncthreads();
    for (int dlt = 1; dlt < 256; dlt <<= 1) {
        int u = (hf >= dlt) ? sh[t - dlt] : 0;
        __syncthreads();
        sh[t] += u;
        __syncthreads();
    }
    int excl = (hf == 0) ? 0 : sh[t - 1];
    if (t < 256) { if (hf < NBLK) partials[hf] = excl; }
    else         { if (hf < NBLK) partials[NBLK + hf] = excl; }
    if (t == NBLK - 1)       off_s[N_NODES] = sh[t];
    if (t == 256 + NBLK - 1) off_d[N_NODES] = sh[t];
}

// Phase C: in-block exclusive scan + block offset -> off arrays.
__global__ __launch_bounds__(SCAN_B)
void final_kernel(const int* __restrict__ deg_s, const int* __restrict__ deg_d,
                  const int* __restrict__ partials,
                  int* __restrict__ off_s, int* __restrict__ off_d)
{
    __shared__ int wsum[4];
    int half = (blockIdx.x < NBLK) ? 0 : 1;
    int blk = half ? (blockIdx.x - NBLK) : blockIdx.x;
    const int* deg = half ? deg_d : deg_s;
    int* off = half ? off_d : off_s;
    int idx = blk * SCAN_B + threadIdx.x;
    int val = (idx < N_NODES) ? deg[idx] : 0;
    int lane = threadIdx.x & 63, wid = threadIdx.x >> 6;
    // inclusive wave scan
    int x = val;
#pragma unroll
    for (int dlt = 1; dlt < 64; dlt <<= 1) {
        int y = __shfl_up(x, dlt, 64);
        if (lane >= dlt) x += y;
    }
    if (lane == 63) wsum[wid] = x;
    __syncthreads();
    int woff = 0;
    for (int w = 0; w < wid; w++) woff += wsum[w];
    int excl = x - val + woff + partials[blockIdx.x];
    if (idx < N_NODES) off[idx] = excl;
}

// ---------------- placement: plain writes, no atomics -----------------------
__global__ __launch_bounds__(256)
void place_kernel(const int* __restrict__ ei, const int* __restrict__ off_s,
                  const int* __restrict__ off_d,
                  const unsigned short* __restrict__ rank_s,
                  const unsigned short* __restrict__ rank_d,
                  int* __restrict__ adj_dst, int* __restrict__ adj_src)
{
    int e = blockIdx.x * 256 + threadIdx.x;
    if (e >= ET) return;
    int s, d;
    if (e < E_EDGES) { s = ei[e]; d = ei[E_EDGES + e]; }
    else { s = d = e - E_EDGES; }
    adj_dst[off_s[s] + rank_s[e]] = d;
    adj_src[off_d[d] + rank_d[e]] = s;
}

// ---------------- esum: per-src gather over by-src CSR (no atomics) ---------
__global__ __launch_bounds__(256)
void esum_kernel(const int* __restrict__ off_s, const int* __restrict__ adj_dst,
                 const float* __restrict__ a_i, const float* __restrict__ a_j,
                 float* __restrict__ esum)
{
    int tid = blockIdx.x * 256 + threadIdx.x;
    int node = tid >> 2;
    if (node >= N_NODES) return;
    int h = tid & 3;
    int start = off_s[node], end = off_s[node + 1];
    float ajh = a_j[node * 4 + h];
    float acc = 0.f;
    for (int i = start; i < end; i++) {
        int d = adj_dst[i];
        float al = a_i[d * 4 + h] + ajh;
        al = al > 0.f ? al : NEG_SLOPE * al;
        acc += __expf(al);
    }
    esum[node * 4 + h] = acc;
}

// ---------------- coef: per-position softmax coefficient (by-dst CSR) -------
// Round-9: aggregate was VALU-bound (62%) computing exp/div 16x-duplicated
// per lane. Precompute coef[pos][h] once: 3.4M exp+div instead of 54M.
__global__ __launch_bounds__(256)
void coef_kernel(const int* __restrict__ off_d, const int* __restrict__ adj_src,
                 const float* __restrict__ a_i, const float* __restrict__ a_j,
                 const float* __restrict__ esum, float* __restrict__ coef)
{
    int tid = blockIdx.x * 256 + threadIdx.x;
    int node = tid >> 2;
    if (node >= N_NODES) return;
    int h = tid & 3;
    int start = off_d[node], end = off_d[node + 1];
    float aih = a_i[node * 4 + h];
    for (int i = start; i < end; i++) {
        int s = adj_src[i];
        float al = aih + a_j[s * 4 + h];
        al = al > 0.f ? al : NEG_SLOPE * al;
        coef[i * 4 + h] = __expf(al) / (esum[s * 4 + h] + 1e-16f);
    }
}

// ---------------- aggregate: one wave per dst node, precomputed coef --------
__global__ __launch_bounds__(256)
void aggregate(const int* __restrict__ off, const int* __restrict__ srcsorted,
               const float* __restrict__ coef, const unsigned* __restrict__ xb32,
               const float* __restrict__ bias, float* __restrict__ out)
{
    int node = blockIdx.x * 4 + (threadIdx.x >> 6);
    if (node >= N_NODES) return;
    int lane = threadIdx.x & 63;
    int h = lane >> 4;                 // head of channels (2*lane, 2*lane+1)
    int start = off[node], end = off[node + 1];
    int n = end - start;
    float acc0 = 0.f, acc1 = 0.f;

    // 3-stage pipeline: index prefetched 2 ahead, payload 1 ahead
    int sb = (n > 0) ? srcsorted[start] : 0;          // index for iter 0
    float c_a = (n > 0) ? coef[start * 4 + h] : 0.f;
    unsigned xp_a = xb32[sb * 64 + lane];
    sb = (n > 1) ? srcsorted[start + 1] : 0;          // index for iter 1
    for (int i = 0; i < n; i++) {
        int s2 = (i + 2 < n) ? srcsorted[start + i + 2] : 0;    // index i+2
        float c_b = (i + 1 < n) ? coef[(start + i + 1) * 4 + h] : 0.f;
        unsigned xp_b = xb32[sb * 64 + lane];                   // payload i+1
        // compute iter i
        float x0 = __uint_as_float(xp_a << 16);
        float x1 = __uint_as_float(xp_a & 0xFFFF0000u);
        acc0 = fmaf(x0, c_a, acc0);
        acc1 = fmaf(x1, c_a, acc1);
        // shift
        c_a = c_b; xp_a = xp_b; sb = s2;
    }
    float2 o;
    o.x = acc0 + bias[2 * lane];
    o.y = acc1 + bias[2 * lane + 1];
    *(float2*)&out[node * 128 + 2 * lane] = o;
}

extern "C" void kernel_launch(void* const* d_in, const int* in_sizes, int n_in,
                              void* d_out, int out_size, void* d_ws, size_t ws_size,
                              hipStream_t stream)
{
    const float* feat   = (const float*)d_in[0];
    const int*   ei     = (const int*)d_in[1];
    const float* weight = (const float*)d_in[2];
    const float* att    = (const float*)d_in[3];
    const float* bias   = (const float*)d_in[4];
    float* out = (float*)d_out;
    char* ws = (char*)d_ws;

    // workspace layout. rank_s/rank_d are TEMP and overlaid on the xb region:
    // consumed by place_kernel BEFORE gemm_kernel writes xb (stream-ordered).
    unsigned short* rank_s = (unsigned short*)ws;        // [0, 1.7M) TEMP
    unsigned short* rank_d = (unsigned short*)(ws + 1700000); // [1.7M, 3.4M) TEMP
    unsigned short* xb = (unsigned short*)ws;            // [0, 12.8M) after place
    float* a_i   = (float*)(ws + 12800000);              //    800,000 B
    float* a_j   = (float*)(ws + 13600000);              //    800,000 B
    float* esum  = (float*)(ws + 14400000);              //    800,000 B
    int*   deg_s = (int*)(ws + 15200000);                //    200,000 B
    int*   deg_d = (int*)(ws + 15400000);                //    200,000 B
    int*   off_s = (int*)(ws + 15600000);                //    200,004 B
    int*   off_d = (int*)(ws + 15800016);                //    200,004 B
    int*   adj_dst = (int*)(ws + 16000032);              //  3,400,000 B (by-src CSR)
    int*   adj_src = (int*)(ws + 19400032);              //  3,400,000 B (by-dst CSR)
    int*   partials = (int*)(ws + 22800032);             //      1,568 B (2*NBLK)
    float* coef  = (float*)(ws + 22801600);              // 13,600,000 B (ET*4 f32)

    // zero deg_s + deg_d (contiguous 400 KB)
    hipMemsetAsync(ws + 15200000, 0, 400000, stream);

    rank_pass<<<(ET + 255) / 256, 256, 0, stream>>>(ei, deg_s, deg_d, rank_s, rank_d);
    partial_kernel<<<2 * NBLK, SCAN_B, 0, stream>>>(deg_s, deg_d, partials);
    scanp_kernel<<<1, 512, 0, stream>>>(partials, off_s, off_d);
    final_kernel<<<2 * NBLK, SCAN_B, 0, stream>>>(deg_s, deg_d, partials, off_s, off_d);
    place_kernel<<<(ET + 255) / 256, 256, 0, stream>>>(ei, off_s, off_d, rank_s, rank_d,
                                                       adj_dst, adj_src);
    gemm_kernel<<<(N_NODES + 63) / 64, 256, 0, stream>>>(feat, weight, att, xb, a_i, a_j);
    esum_kernel<<<(4 * N_NODES + 255) / 256, 256, 0, stream>>>(off_s, adj_dst, a_i, a_j, esum);
    coef_kernel<<<(4 * N_NODES + 255) / 256, 256, 0, stream>>>(off_d, adj_src, a_i, a_j,
                                                               esum, coef);
    aggregate<<<(N_NODES + 3) / 4, 256, 0, stream>>>(off_d, adj_src, coef,
                                                     (const unsigned*)xb, bias, out);
}

// Round 13
// 279.346 us; speedup vs baseline: 1.1889x; 1.1889x over previous
//
#include <hip/hip_runtime.h>
#include <hip/hip_bf16.h>

#define N_NODES 50000
#define E_EDGES 800000
#define ET (E_EDGES + N_NODES)   // with self-loops
#define HEADS 4
#define HC 128                    // HEADS * OUT_CH
#define NEG_SLOPE 0.2f
#define SCAN_B 256
#define NBLK ((N_NODES + SCAN_B - 1) / SCAN_B)   // 196 blocks per array

__device__ __forceinline__ unsigned short f2bf(float f) {
    unsigned u = __float_as_uint(f);
    unsigned r = u + 0x7FFFu + ((u >> 16) & 1u);
    return (unsigned short)(r >> 16);
}

// ---------------- GEMM: x = feat @ W, fused a_i/a_j epilogue ----------------
// (unchanged from round 7: shuffle-reduce epilogue, no atomics)
__global__ __launch_bounds__(256)
void gemm_kernel(const float* __restrict__ feat, const float* __restrict__ weight,
                 const float* __restrict__ att,
                 unsigned short* __restrict__ xb,    // bf16 x, [N][128]
                 float* __restrict__ a_i, float* __restrict__ a_j)
{
    __shared__ float sA[32][68];   // [k][row] transposed, BM=64
    __shared__ float sB[32][132];  // [k][col], BN=128
    const int t = threadIdx.x;
    const int row0 = blockIdx.x * 64;
    const int rg = t >> 4;   // 0..15 -> rows 4rg..4rg+3
    const int cg = t & 15;   // 0..15 -> cols 4cg..+3, 64+4cg..+3

    float acc[4][8];
#pragma unroll
    for (int i = 0; i < 4; i++)
#pragma unroll
        for (int j = 0; j < 8; j++) acc[i][j] = 0.f;

    for (int kc = 0; kc < 128; kc += 32) {
        __syncthreads();
#pragma unroll
        for (int q = 0; q < 2; q++) {          // stage feat tile (transposed)
            int qi = t + q * 256;              // 0..511
            int row = qi >> 3;                 // 0..63
            int kq = qi & 7;                   // 0..7
            int grow = row0 + row;
            float4 v = make_float4(0.f, 0.f, 0.f, 0.f);
            if (grow < N_NODES)
                v = *(const float4*)&feat[grow * 128 + kc + kq * 4];
            sA[kq * 4 + 0][row] = v.x; sA[kq * 4 + 1][row] = v.y;
            sA[kq * 4 + 2][row] = v.z; sA[kq * 4 + 3][row] = v.w;
        }
#pragma unroll
        for (int q = 0; q < 4; q++) {          // stage W tile
            int qi = t + q * 256;
            int k = qi >> 5;                   // 0..31
            int cq = qi & 31;                  // 0..31
            float4 v = *(const float4*)&weight[(kc + k) * 128 + cq * 4];
            *(float4*)&sB[k][cq * 4] = v;
        }
        __syncthreads();
#pragma unroll 4
        for (int k = 0; k < 32; k++) {
            float4 a0 = *(const float4*)&sA[k][4 * rg];
            float4 b0 = *(const float4*)&sB[k][4 * cg];
            float4 b1 = *(const float4*)&sB[k][64 + 4 * cg];
#define FMA_ROW(r, ar) \
            acc[r][0] = fmaf(ar, b0.x, acc[r][0]); \
            acc[r][1] = fmaf(ar, b0.y, acc[r][1]); \
            acc[r][2] = fmaf(ar, b0.z, acc[r][2]); \
            acc[r][3] = fmaf(ar, b0.w, acc[r][3]); \
            acc[r][4] = fmaf(ar, b1.x, acc[r][4]); \
            acc[r][5] = fmaf(ar, b1.y, acc[r][5]); \
            acc[r][6] = fmaf(ar, b1.z, acc[r][6]); \
            acc[r][7] = fmaf(ar, b1.w, acc[r][7]);
            FMA_ROW(0, a0.x)
            FMA_ROW(1, a0.y)
            FMA_ROW(2, a0.z)
            FMA_ROW(3, a0.w)
#undef FMA_ROW
        }
    }

    // epilogue: bf16 store + shuffle-reduced a_i/a_j (NO atomics)
    const int h0 = cg >> 3;              // head of col group 0 (0 or 1)
    const int cih = (4 * cg) & 31;       // col within head
    float ai_c[2][4], aj_c[2][4];
#pragma unroll
    for (int g = 0; g < 2; g++) {
        int h = h0 + g * 2;
#pragma unroll
        for (int j = 0; j < 4; j++) {
            ai_c[g][j] = att[h * 64 + cih + j];
            aj_c[g][j] = att[h * 64 + 32 + cih + j];
        }
    }
#pragma unroll
    for (int i = 0; i < 4; i++) {
        int row = row0 + 4 * rg + i;
        if (row >= N_NODES) continue;      // uniform across each 8-lane group
        unsigned p0 = (unsigned)f2bf(acc[i][0]) | ((unsigned)f2bf(acc[i][1]) << 16);
        unsigned p1 = (unsigned)f2bf(acc[i][2]) | ((unsigned)f2bf(acc[i][3]) << 16);
        unsigned p2 = (unsigned)f2bf(acc[i][4]) | ((unsigned)f2bf(acc[i][5]) << 16);
        unsigned p3 = (unsigned)f2bf(acc[i][6]) | ((unsigned)f2bf(acc[i][7]) << 16);
        uint2 q0; q0.x = p0; q0.y = p1;
        uint2 q1; q1.x = p2; q1.y = p3;
        *(uint2*)&xb[row * 128 + 4 * cg] = q0;
        *(uint2*)&xb[row * 128 + 64 + 4 * cg] = q1;

        float pi0 = 0.f, pj0 = 0.f, pi1 = 0.f, pj1 = 0.f;
#pragma unroll
        for (int j = 0; j < 4; j++) {
            pi0 = fmaf(acc[i][j], ai_c[0][j], pi0);
            pj0 = fmaf(acc[i][j], aj_c[0][j], pj0);
            pi1 = fmaf(acc[i][4 + j], ai_c[1][j], pi1);
            pj1 = fmaf(acc[i][4 + j], aj_c[1][j], pj1);
        }
        // butterfly over cg bits 0..2 (8 lanes hold one (row,head) partial)
#pragma unroll
        for (int m = 1; m <= 4; m <<= 1) {
            pi0 += __shfl_xor(pi0, m, 64);
            pj0 += __shfl_xor(pj0, m, 64);
            pi1 += __shfl_xor(pi1, m, 64);
            pj1 += __shfl_xor(pj1, m, 64);
        }
        if ((cg & 7) == 0) {               // cg==0 -> heads 0,2; cg==8 -> heads 1,3
            a_i[row * 4 + h0]     = pi0;
            a_i[row * 4 + h0 + 2] = pi1;
            a_j[row * 4 + h0]     = pj0;
            a_j[row * 4 + h0 + 2] = pj1;
        }
    }
}

// ---------------- rank pass: deg histograms, return-value = rank ------------
__global__ __launch_bounds__(256)
void rank_pass(const int* __restrict__ ei, int* __restrict__ deg_s,
               int* __restrict__ deg_d, unsigned short* __restrict__ rank_s,
               unsigned short* __restrict__ rank_d)
{
    int e = blockIdx.x * 256 + threadIdx.x;
    if (e >= ET) return;
    int s, d;
    if (e < E_EDGES) { s = ei[e]; d = ei[E_EDGES + e]; }
    else { s = d = e - E_EDGES; }
    rank_s[e] = (unsigned short)atomicAdd(&deg_s[s], 1);
    rank_d[e] = (unsigned short)atomicAdd(&deg_d[d], 1);
}

// ---------------- hierarchical scan (3-phase, multi-block) ------------------
__global__ __launch_bounds__(SCAN_B)
void partial_kernel(const int* __restrict__ deg_s, const int* __restrict__ deg_d,
                    int* __restrict__ partials)
{
    __shared__ int wsum[4];
    int half = (blockIdx.x < NBLK) ? 0 : 1;
    int blk = half ? (blockIdx.x - NBLK) : blockIdx.x;
    const int* deg = half ? deg_d : deg_s;
    int idx = blk * SCAN_B + threadIdx.x;
    int v = (idx < N_NODES) ? deg[idx] : 0;
#pragma unroll
    for (int m = 1; m < 64; m <<= 1) v += __shfl_xor(v, m, 64);
    int lane = threadIdx.x & 63, wid = threadIdx.x >> 6;
    if (lane == 0) wsum[wid] = v;
    __syncthreads();
    if (threadIdx.x == 0)
        partials[blockIdx.x] = wsum[0] + wsum[1] + wsum[2] + wsum[3];
}

__global__ __launch_bounds__(512)
void scanp_kernel(int* __restrict__ partials, int* __restrict__ off_s,
                  int* __restrict__ off_d)
{
    __shared__ int sh[512];
    int t = threadIdx.x;
    int hf = t & 255;
    int v = 0;
    if (t < 256)      v = (hf < NBLK) ? partials[hf] : 0;
    else              v = (hf < NBLK) ? partials[NBLK + hf] : 0;
    sh[t] = v;
    __syncthreads();
    for (int dlt = 1; dlt < 256; dlt <<= 1) {
        int u = (hf >= dlt) ? sh[t - dlt] : 0;
        __syncthreads();
        sh[t] += u;
        __syncthreads();
    }
    int excl = (hf == 0) ? 0 : sh[t - 1];
    if (t < 256) { if (hf < NBLK) partials[hf] = excl; }
    else         { if (hf < NBLK) partials[NBLK + hf] = excl; }
    if (t == NBLK - 1)       off_s[N_NODES] = sh[t];
    if (t == 256 + NBLK - 1) off_d[N_NODES] = sh[t];
}

__global__ __launch_bounds__(SCAN_B)
void final_kernel(const int* __restrict__ deg_s, const int* __restrict__ deg_d,
                  const int* __restrict__ partials,
                  int* __restrict__ off_s, int* __restrict__ off_d)
{
    __shared__ int wsum[4];
    int half = (blockIdx.x < NBLK) ? 0 : 1;
    int blk = half ? (blockIdx.x - NBLK) : blockIdx.x;
    const int* deg = half ? deg_d : deg_s;
    int* off = half ? off_d : off_s;
    int idx = blk * SCAN_B + threadIdx.x;
    int val = (idx < N_NODES) ? deg[idx] : 0;
    int lane = threadIdx.x & 63, wid = threadIdx.x >> 6;
    int x = val;
#pragma unroll
    for (int dlt = 1; dlt < 64; dlt <<= 1) {
        int y = __shfl_up(x, dlt, 64);
        if (lane >= dlt) x += y;
    }
    if (lane == 63) wsum[wid] = x;
    __syncthreads();
    int woff = 0;
    for (int w = 0; w < wid; w++) woff += wsum[w];
    int excl = x - val + woff + partials[blockIdx.x];
    if (idx < N_NODES) off[idx] = excl;
}

// ---------------- placement: plain writes, no atomics -----------------------
__global__ __launch_bounds__(256)
void place_kernel(const int* __restrict__ ei, const int* __restrict__ off_s,
                  const int* __restrict__ off_d,
                  const unsigned short* __restrict__ rank_s,
                  const unsigned short* __restrict__ rank_d,
                  int* __restrict__ adj_dst, int* __restrict__ adj_src)
{
    int e = blockIdx.x * 256 + threadIdx.x;
    if (e >= ET) return;
    int s, d;
    if (e < E_EDGES) { s = ei[e]; d = ei[E_EDGES + e]; }
    else { s = d = e - E_EDGES; }
    adj_dst[off_s[s] + rank_s[e]] = d;
    adj_src[off_d[d] + rank_d[e]] = s;
}

// ---------------- esum: per-src gather, group-4 pipeline --------------------
// Round-10: depth-1 dependent-gather loops are latency-bound (aggregate VALU
// 30%, 1.3TB/s, dur unchanged when VALU removed). Group-4: 4 gathers in
// flight per round-trip. Accumulation order unchanged (k ascending).
__global__ __launch_bounds__(256)
void esum_kernel(const int* __restrict__ off_s, const int* __restrict__ adj_dst,
                 const float* __restrict__ a_i, const float* __restrict__ a_j,
                 float* __restrict__ esum)
{
    int tid = blockIdx.x * 256 + threadIdx.x;
    int node = tid >> 2;
    if (node >= N_NODES) return;
    int h = tid & 3;
    int start = off_s[node], end = off_s[node + 1];
    float ajh = a_j[node * 4 + h];
    float acc = 0.f;
    int s_cur[4];
#pragma unroll
    for (int k = 0; k < 4; k++)
        s_cur[k] = (start + k < end) ? adj_dst[start + k] : 0;
    for (int i0 = start; i0 < end; i0 += 4) {
        int i1 = i0 + 4;
        int s_nxt[4];
#pragma unroll
        for (int k = 0; k < 4; k++)
            s_nxt[k] = (i1 + k < end) ? adj_dst[i1 + k] : 0;
        float aiv[4];
#pragma unroll
        for (int k = 0; k < 4; k++)
            aiv[k] = a_i[s_cur[k] * 4 + h];
#pragma unroll
        for (int k = 0; k < 4; k++) {
            if (i0 + k < end) {
                float al = aiv[k] + ajh;
                al = al > 0.f ? al : NEG_SLOPE * al;
                acc += __expf(al);
            }
        }
#pragma unroll
        for (int k = 0; k < 4; k++) s_cur[k] = s_nxt[k];
    }
    esum[node * 4 + h] = acc;
}

// ---------------- coef: per-position coefficient, group-4 pipeline ----------
__global__ __launch_bounds__(256)
void coef_kernel(const int* __restrict__ off_d, const int* __restrict__ adj_src,
                 const float* __restrict__ a_i, const float* __restrict__ a_j,
                 const float* __restrict__ esum, float* __restrict__ coef)
{
    int tid = blockIdx.x * 256 + threadIdx.x;
    int node = tid >> 2;
    if (node >= N_NODES) return;
    int h = tid & 3;
    int start = off_d[node], end = off_d[node + 1];
    float aih = a_i[node * 4 + h];
    int s_cur[4];
#pragma unroll
    for (int k = 0; k < 4; k++)
        s_cur[k] = (start + k < end) ? adj_src[start + k] : 0;
    for (int i0 = start; i0 < end; i0 += 4) {
        int i1 = i0 + 4;
        int s_nxt[4];
#pragma unroll
        for (int k = 0; k < 4; k++)
            s_nxt[k] = (i1 + k < end) ? adj_src[i1 + k] : 0;
        float ajv[4], esv[4];
#pragma unroll
        for (int k = 0; k < 4; k++) {
            ajv[k] = a_j[s_cur[k] * 4 + h];
            esv[k] = esum[s_cur[k] * 4 + h];
        }
#pragma unroll
        for (int k = 0; k < 4; k++) {
            if (i0 + k < end) {
                float al = aih + ajv[k];
                al = al > 0.f ? al : NEG_SLOPE * al;
                coef[(i0 + k) * 4 + h] = __expf(al) / (esv[k] + 1e-16f);
            }
        }
#pragma unroll
        for (int k = 0; k < 4; k++) s_cur[k] = s_nxt[k];
    }
}

// ---------------- aggregate: one wave per dst node, group-4 pipeline --------
__global__ __launch_bounds__(256)
void aggregate(const int* __restrict__ off, const int* __restrict__ srcsorted,
               const float* __restrict__ coef, const unsigned* __restrict__ xb32,
               const float* __restrict__ bias, float* __restrict__ out)
{
    int node = blockIdx.x * 4 + (threadIdx.x >> 6);
    if (node >= N_NODES) return;
    int lane = threadIdx.x & 63;
    int h = lane >> 4;                 // head of channels (2*lane, 2*lane+1)
    int start = off[node], end = off[node + 1];
    float acc0 = 0.f, acc1 = 0.f;

    // group-4 pipeline: next group's indices+coefs load during current
    // group's payload gathers; invalid slots padded with c=0 (FMA no-op).
    int s_cur[4]; float c_cur[4];
#pragma unroll
    for (int k = 0; k < 4; k++) {
        bool v = (start + k < end);
        s_cur[k] = v ? srcsorted[start + k] : 0;
        c_cur[k] = v ? coef[(start + k) * 4 + h] : 0.f;
    }
    for (int i0 = start; i0 < end; i0 += 4) {
        int i1 = i0 + 4;
        int s_nxt[4]; float c_nxt[4];
#pragma unroll
        for (int k = 0; k < 4; k++) {
            bool v = (i1 + k < end);
            s_nxt[k] = v ? srcsorted[i1 + k] : 0;
            c_nxt[k] = v ? coef[(i1 + k) * 4 + h] : 0.f;
        }
        unsigned xp[4];
#pragma unroll
        for (int k = 0; k < 4; k++)
            xp[k] = xb32[s_cur[k] * 64 + lane];
#pragma unroll
        for (int k = 0; k < 4; k++) {
            float x0 = __uint_as_float(xp[k] << 16);
            float x1 = __uint_as_float(xp[k] & 0xFFFF0000u);
            acc0 = fmaf(x0, c_cur[k], acc0);
            acc1 = fmaf(x1, c_cur[k], acc1);
        }
#pragma unroll
        for (int k = 0; k < 4; k++) { s_cur[k] = s_nxt[k]; c_cur[k] = c_nxt[k]; }
    }
    float2 o;
    o.x = acc0 + bias[2 * lane];
    o.y = acc1 + bias[2 * lane + 1];
    *(float2*)&out[node * 128 + 2 * lane] = o;
}

extern "C" void kernel_launch(void* const* d_in, const int* in_sizes, int n_in,
                              void* d_out, int out_size, void* d_ws, size_t ws_size,
                              hipStream_t stream)
{
    const float* feat   = (const float*)d_in[0];
    const int*   ei     = (const int*)d_in[1];
    const float* weight = (const float*)d_in[2];
    const float* att    = (const float*)d_in[3];
    const float* bias   = (const float*)d_in[4];
    float* out = (float*)d_out;
    char* ws = (char*)d_ws;

    // workspace layout. rank_s/rank_d are TEMP and overlaid on the xb region:
    // consumed by place_kernel BEFORE gemm_kernel writes xb (stream-ordered).
    unsigned short* rank_s = (unsigned short*)ws;        // [0, 1.7M) TEMP
    unsigned short* rank_d = (unsigned short*)(ws + 1700000); // [1.7M, 3.4M) TEMP
    unsigned short* xb = (unsigned short*)ws;            // [0, 12.8M) after place
    float* a_i   = (float*)(ws + 12800000);              //    800,000 B
    float* a_j   = (float*)(ws + 13600000);              //    800,000 B
    float* esum  = (float*)(ws + 14400000);              //    800,000 B
    int*   deg_s = (int*)(ws + 15200000);                //    200,000 B
    int*   deg_d = (int*)(ws + 15400000);                //    200,000 B
    int*   off_s = (int*)(ws + 15600000);                //    200,004 B
    int*   off_d = (int*)(ws + 15800016);                //    200,004 B
    int*   adj_dst = (int*)(ws + 16000032);              //  3,400,000 B (by-src CSR)
    int*   adj_src = (int*)(ws + 19400032);              //  3,400,000 B (by-dst CSR)
    int*   partials = (int*)(ws + 22800032);             //      1,568 B (2*NBLK)
    float* coef  = (float*)(ws + 22801600);              // 13,600,000 B (ET*4 f32)

    // zero deg_s + deg_d (contiguous 400 KB)
    hipMemsetAsync(ws + 15200000, 0, 400000, stream);

    rank_pass<<<(ET + 255) / 256, 256, 0, stream>>>(ei, deg_s, deg_d, rank_s, rank_d);
    partial_kernel<<<2 * NBLK, SCAN_B, 0, stream>>>(deg_s, deg_d, partials);
    scanp_kernel<<<1, 512, 0, stream>>>(partials, off_s, off_d);
    final_kernel<<<2 * NBLK, SCAN_B, 0, stream>>>(deg_s, deg_d, partials, off_s, off_d);
    place_kernel<<<(ET + 255) / 256, 256, 0, stream>>>(ei, off_s, off_d, rank_s, rank_d,
                                                       adj_dst, adj_src);
    gemm_kernel<<<(N_NODES + 63) / 64, 256, 0, stream>>>(feat, weight, att, xb, a_i, a_j);
    esum_kernel<<<(4 * N_NODES + 255) / 256, 256, 0, stream>>>(off_s, adj_dst, a_i, a_j, esum);
    coef_kernel<<<(4 * N_NODES + 255) / 256, 256, 0, stream>>>(off_d, adj_src, a_i, a_j,
                                                               esum, coef);
    aggregate<<<(N_NODES + 3) / 4, 256, 0, stream>>>(off_d, adj_src, coef,
                                                     (const unsigned*)xb, bias, out);
}